// Round 7
// baseline (293.030 us; speedup 1.0000x reference)
//
#include <hip/hip_runtime.h>
#include <stdint.h>

#define TTOK 1024
#define DMODEL 1024
#define NEXP 16
#define TOPK 4
#define INTER 512
#define NSHI 1024
#define RSCALE 2.5f

typedef __bf16 bf16;
typedef __bf16 bf16x8 __attribute__((ext_vector_type(8)));
typedef __bf16 bf16x4 __attribute__((ext_vector_type(4)));
typedef float f32x4 __attribute__((ext_vector_type(4)));

// LDS plane strides (+16B pad)
#define APL 4112   // 256 rows * 16B + 16
#define BPL32 528  // 32 rows * 16B + 16
#define BPL128 2064  // 128 rows * 16B + 16
#define ASZ (4 * APL)
#define BSZ32 (4 * BPL32)
#define BSZ128 (4 * BPL128)

__device__ __forceinline__ void glds16(void* lds, const void* g) {
  __builtin_amdgcn_global_load_lds(
      (const __attribute__((address_space(1))) unsigned int*)g,
      (__attribute__((address_space(3))) unsigned int*)lds, 16, 0, 0);
}

// ---------------- scores (+ fused x->bf16) ----------------
__global__ __launch_bounds__(256)
void scores_kernel(const float* __restrict__ x, const float* __restrict__ gw,
                   float* __restrict__ scores, bf16* __restrict__ xbf) {
  __shared__ float gws[16 * 1024];
  const int tid = threadIdx.x;
  const float4* gw4 = (const float4*)gw;
#pragma unroll
  for (int i0 = 0; i0 < 4096; i0 += 256) {
    const int i = i0 + tid;
    const int e = i >> 8;
    const int dq = (i & 255) << 2;
    const int dd = (dq + 4 * e) & 1023;
    ((float4*)gws)[(e << 8) + (dd >> 2)] = gw4[i];
  }
  {
    const long xb = (long)blockIdx.x * 1024;
#pragma unroll
    for (int p = 0; p < 4; ++p) {
      const long j = xb + p * 256 + tid;
      const float4 v = ((const float4*)x)[j];
      bf16x4 o;
      o.x = (bf16)v.x; o.y = (bf16)v.y; o.z = (bf16)v.z; o.w = (bf16)v.w;
      ((bf16x4*)xbf)[j] = o;
    }
  }
  __syncthreads();
  const int kq = tid >> 6;
  const int lane = tid & 63;
  const int tl = lane >> 4;
  const int e = lane & 15;
  const long token = (long)blockIdx.x * 4 + tl;
  float acc = 0.f;
  const int dbase = kq * 256;
#pragma unroll 8
  for (int i = 0; i < 256; i += 4) {
    const int d = dbase + i;
    const float4 xv = *(const float4*)&x[token * DMODEL + d];
    const float4 wv = *(const float4*)&gws[(e << 10) + ((d + 4 * e) & 1023)];
    acc += xv.x * wv.x + xv.y * wv.y + xv.z * wv.z + xv.w * wv.w;
  }
  __syncthreads();
  gws[kq * 64 + lane] = acc;
  __syncthreads();
  if (kq == 0) {
    const float s = gws[lane] + gws[64 + lane] + gws[128 + lane] + gws[192 + lane];
    scores[token * 16 + e] = s;
  }
}

// ---------------- top-k ----------------
__global__ __launch_bounds__(256)
void topk_kernel(const float* __restrict__ scores, const float* __restrict__ gb,
                 int* __restrict__ tokIdx, float* __restrict__ tokW,
                 int* __restrict__ counts) {
  __shared__ int h[NEXP];
  const int tid = threadIdx.x;
  if (tid < NEXP) h[tid] = 0;
  __syncthreads();
  const int t = blockIdx.x * 256 + tid;
  float sc[NEXP], s[NEXP];
#pragma unroll
  for (int e = 0; e < NEXP; ++e) {
    const float l = scores[t * NEXP + e];
    sc[e] = 1.f / (1.f + expf(-l));
    s[e] = sc[e] + gb[e];
  }
  float gsc[4];
#pragma unroll
  for (int g = 0; g < 4; ++g) {
    const float a = s[4 * g], b = s[4 * g + 1], c = s[4 * g + 2], d = s[4 * g + 3];
    gsc[g] = fmaxf(fmaxf(fmaxf(a + b, a + c), fmaxf(a + d, b + c)),
                   fmaxf(b + d, c + d));
  }
  int g0 = 0;
  for (int g = 1; g < 4; ++g) if (gsc[g] > gsc[g0]) g0 = g;
  int g1 = (g0 == 0) ? 1 : 0;
  for (int g = 0; g < 4; ++g) if (g != g0 && gsc[g] > gsc[g1]) g1 = g;
  float m[NEXP];
#pragma unroll
  for (int e = 0; e < NEXP; ++e) {
    const int g = e >> 2;
    m[e] = (g == g0 || g == g1) ? s[e] : -1.f;
  }
  int idx[TOPK]; float wv[TOPK]; float wsum = 0.f;
  for (int k = 0; k < TOPK; ++k) {
    int am = 0; float best = m[0];
    for (int e2 = 1; e2 < NEXP; ++e2)
      if (m[e2] > best) { best = m[e2]; am = e2; }
    idx[k] = am; wv[k] = sc[am]; wsum += sc[am]; m[am] = -2.f;
  }
  const float scl = RSCALE / wsum;
  for (int k = 0; k < TOPK; ++k) {
    tokIdx[t * TOPK + k] = idx[k];
    tokW[t * TOPK + k] = wv[k] * scl;
    atomicAdd(&h[idx[k]], 1);
  }
  __syncthreads();
  if (tid < NEXP) atomicAdd(&counts[tid], h[tid]);
}

// ---------------- plan: offsets + tile list (M-step 256) ----------------
__global__ void plan_kernel(const int* __restrict__ counts, int* __restrict__ offs,
                            int* __restrict__ cursors, int* __restrict__ tileE,
                            int* __restrict__ tileR, int* __restrict__ tileCnt) {
  if (threadIdx.x == 0) {
    int acc = 0;
    for (int e = 0; e < NEXP; ++e) { offs[e] = acc; cursors[e] = acc; acc += counts[e]; }
    offs[NEXP] = acc;
    int tc = 0;
    for (int e = 0; e < NEXP; ++e)
      for (int r = offs[e]; r < offs[e + 1]; r += 256) { tileE[tc] = e; tileR[tc] = r; ++tc; }
    for (int r = 0; r < TTOK; r += 256) { tileE[tc] = NEXP; tileR[tc] = r; ++tc; }
    tileCnt[0] = tc;  // typically ~20-24, worst 35
  }
}

// ---------------- fill ----------------
__global__ __launch_bounds__(256)
void fill_kernel(const int* __restrict__ tokIdx, int* __restrict__ cursors,
                 int* __restrict__ slotTok, int* __restrict__ tokSlot) {
  __shared__ int h[NEXP], base[NEXP];
  const int tid = threadIdx.x;
  if (tid < NEXP) h[tid] = 0;
  __syncthreads();
  const int t = blockIdx.x * 256 + tid;
  int myE[TOPK], myR[TOPK];
#pragma unroll
  for (int k = 0; k < TOPK; ++k) {
    myE[k] = tokIdx[t * TOPK + k];
    myR[k] = atomicAdd(&h[myE[k]], 1);
  }
  __syncthreads();
  if (tid < NEXP) base[tid] = atomicAdd(&cursors[tid], h[tid]);
  __syncthreads();
#pragma unroll
  for (int k = 0; k < TOPK; ++k) {
    const int slot = base[myE[k]] + myR[k];
    slotTok[slot] = t;
    tokSlot[t * TOPK + k] = slot;
  }
}

// ---------------- gate+up GEMM: 256M x 32N, BK=32, LDS dbuf, 1 barrier/iter ----------------
__global__ __launch_bounds__(256, 3)
void gateup_gemm(const bf16* __restrict__ xbf, const int* __restrict__ slotTok,
                 const int* __restrict__ offs, const int* __restrict__ tileE,
                 const int* __restrict__ tileR, const int* __restrict__ tileCnt,
                 const float* __restrict__ Wg, const float* __restrict__ Wu,
                 const float* __restrict__ Sg, const float* __restrict__ Su,
                 bf16* __restrict__ interR, bf16* __restrict__ interS) {
  const int y = blockIdx.y;
  if (y >= tileCnt[0]) return;
  const int e = tileE[y];
  const bool shd = (e == NEXP);
  const int n0 = blockIdx.x * 32;
  if (!shd && n0 >= INTER) return;
  const int rowStart = tileR[y];
  const int rowEnd = shd ? rowStart + 256 : offs[e + 1];
  const float* wgp = shd ? Sg : Wg + (long)e * INTER * DMODEL;
  const float* wup = shd ? Su : Wu + (long)e * INTER * DMODEL;

  __shared__ __attribute__((aligned(16))) char As[2 * ASZ];
  __shared__ __attribute__((aligned(16))) char Bg[2 * BSZ32];
  __shared__ __attribute__((aligned(16))) char Bu[2 * BSZ32];
  __shared__ int tokS[256];

  const int tid = threadIdx.x;
  {
    const int r = rowStart + tid;
    tokS[tid] = shd ? (r < TTOK ? r : rowStart)
                    : slotTok[r < rowEnd ? r : rowStart];
  }
  __syncthreads();

  const int lane = tid & 63;
  const int wv = tid >> 6;
  // A: wave wv stages oct plane wv; 4 glds16/iter (rows p*64+lane)
  const bf16* aG[4];
#pragma unroll
  for (int p = 0; p < 4; ++p)
    aG[p] = xbf + (long)tokS[p * 64 + lane] * DMODEL + wv * 8;

  // B: 128 threads/matrix; thread: row=u>>2 (0..31), oct=u&3; 2 float4 -> 1 ds_write_b128
  const int mat = tid >> 7;
  const int u = tid & 127;
  const int brow = u >> 2;
  const int boct = u & 3;
  const float* bp = (mat ? wup : wgp) + (long)(n0 + brow) * DMODEL + boct * 8;
  char* bL = (mat ? Bu : Bg);

  const int q = lane >> 4;
  const int l15 = lane & 15;
  const int wm = wv * 64;

  const f32x4 fz = {0.f, 0.f, 0.f, 0.f};
  f32x4 accG[4][2], accU[4][2];
#pragma unroll
  for (int i = 0; i < 4; ++i)
#pragma unroll
    for (int j = 0; j < 2; ++j) { accG[i][j] = fz; accU[i][j] = fz; }

  // prologue: stage k=0 into buf0, prefetch b-regs for k=32
  float4 b0 = *(const float4*)(bp);
  float4 b1 = *(const float4*)(bp + 4);
  {
#pragma unroll
    for (int p = 0; p < 4; ++p)
      glds16(As + wv * APL + (p * 64) * 16, aG[p]);
    bf16x8 w;
    w[0] = (bf16)b0.x; w[1] = (bf16)b0.y; w[2] = (bf16)b0.z; w[3] = (bf16)b0.w;
    w[4] = (bf16)b1.x; w[5] = (bf16)b1.y; w[6] = (bf16)b1.z; w[7] = (bf16)b1.w;
    *(bf16x8*)(bL + boct * BPL32 + brow * 16) = w;
  }
  b0 = *(const float4*)(bp + 32);
  b1 = *(const float4*)(bp + 36);

  int buf = 0;
  for (int k0 = 0; k0 < DMODEL; k0 += 32, buf ^= 1) {
    __syncthreads();  // buf(k0) ready; nxt free
    const int nxt = buf ^ 1;
    const int kn = k0 + 32;
    if (kn < DMODEL) {
      // async A(k0+32) -> nxt
#pragma unroll
      for (int p = 0; p < 4; ++p)
        glds16(As + nxt * ASZ + wv * APL + (p * 64) * 16, aG[p] + kn);
      // B(k0+32) regs -> nxt
      bf16x8 w;
      w[0] = (bf16)b0.x; w[1] = (bf16)b0.y; w[2] = (bf16)b0.z; w[3] = (bf16)b0.w;
      w[4] = (bf16)b1.x; w[5] = (bf16)b1.y; w[6] = (bf16)b1.z; w[7] = (bf16)b1.w;
      *(bf16x8*)(bL + nxt * BSZ32 + boct * BPL32 + brow * 16) = w;
      if (kn + 32 < DMODEL) {
        b0 = *(const float4*)(bp + kn + 32);
        b1 = *(const float4*)(bp + kn + 36);
      }
    }
    // MFMA on buf(k0)
    const char* ab = As + buf * ASZ;
    const char* gb_ = Bg + buf * BSZ32;
    const char* ub = Bu + buf * BSZ32;
    bf16x8 aF[4];
#pragma unroll
    for (int mi = 0; mi < 4; ++mi)
      aF[mi] = *(const bf16x8*)(ab + q * APL + (wm + 16 * mi + l15) * 16);
#pragma unroll
    for (int ni = 0; ni < 2; ++ni) {
      const bf16x8 gF = *(const bf16x8*)(gb_ + q * BPL32 + (16 * ni + l15) * 16);
      const bf16x8 uF = *(const bf16x8*)(ub + q * BPL32 + (16 * ni + l15) * 16);
#pragma unroll
      for (int mi = 0; mi < 4; ++mi) {
        accG[mi][ni] = __builtin_amdgcn_mfma_f32_16x16x32_bf16(aF[mi], gF, accG[mi][ni], 0, 0, 0);
        accU[mi][ni] = __builtin_amdgcn_mfma_f32_16x16x32_bf16(aF[mi], uF, accU[mi][ni], 0, 0, 0);
      }
    }
  }

  bf16* outI = shd ? interS : interR;
  const int ldI = shd ? NSHI : INTER;
#pragma unroll
  for (int mi = 0; mi < 4; ++mi)
#pragma unroll
    for (int r = 0; r < 4; ++r) {
      const int rowLoc = wm + 16 * mi + q * 4 + r;
      const int row = rowStart + rowLoc;
      if (row < rowEnd) {
#pragma unroll
        for (int ni = 0; ni < 2; ++ni) {
          const float gg = accG[mi][ni][r];
          const float uu = accU[mi][ni][r];
          const float sv = gg / (1.f + __expf(-gg)) * uu;
          outI[(long)row * ldI + (n0 + 16 * ni + l15)] = (bf16)sv;
        }
      }
    }
}

// ---------------- down GEMM: 256M x 128N, split-K x2, LDS dbuf, 1 barrier/iter ----------------
__global__ __launch_bounds__(256, 2)
void down_gemm(const bf16* __restrict__ interR, const bf16* __restrict__ interS,
               const int* __restrict__ offs, const int* __restrict__ tileE,
               const int* __restrict__ tileR, const int* __restrict__ tileCnt,
               const float* __restrict__ Wd, const float* __restrict__ Sd,
               float* __restrict__ dsR0, float* __restrict__ dsR1,
               float* __restrict__ dsS0, float* __restrict__ dsS1) {
  const int y = blockIdx.y;
  if (y >= tileCnt[0]) return;
  const int ks = blockIdx.z;
  const int e = tileE[y];
  const bool shd = (e == NEXP);
  const int n0 = blockIdx.x * 128;
  const int rowStart = tileR[y];
  const int rowEnd = shd ? rowStart + 256 : offs[e + 1];
  const int KdF = shd ? NSHI : INTER;
  const int Kh = KdF >> 1;
  const int kb = ks * Kh;
  const bf16* A = shd ? interS : interR;
  const float* wd = shd ? Sd : Wd + (long)e * DMODEL * INTER;

  __shared__ __attribute__((aligned(16))) char As[2 * ASZ];
  __shared__ __attribute__((aligned(16))) char Bs[2 * BSZ128];

  const int tid = threadIdx.x;
  const int lane = tid & 63;
  const int wv = tid >> 6;
  const bf16* aG[4];
#pragma unroll
  for (int p = 0; p < 4; ++p)
    aG[p] = A + (long)(rowStart + p * 64 + lane) * KdF + kb + wv * 8;

  // B: 256 threads; row=tid>>1 (0..127), half h2=tid&1; 4 float4 -> 2 ds_write_b64
  const int brow = tid >> 1;
  const int h2 = tid & 1;
  const float* bp = wd + (long)(n0 + brow) * KdF + kb + h2 * 16;

  const int q = lane >> 4;
  const int l15 = lane & 15;
  const int wm = wv * 64;

  const f32x4 fz = {0.f, 0.f, 0.f, 0.f};
  f32x4 acc[4][8];
#pragma unroll
  for (int i = 0; i < 4; ++i)
#pragma unroll
    for (int j = 0; j < 8; ++j) acc[i][j] = fz;

  float4 bv0, bv1, bv2, bv3;
#define DN_LOADB(K0)                      \
  {                                       \
    bv0 = *(const float4*)(bp + (K0));    \
    bv1 = *(const float4*)(bp + (K0) + 4);  \
    bv2 = *(const float4*)(bp + (K0) + 8);  \
    bv3 = *(const float4*)(bp + (K0) + 12); \
  }
#define DN_WRITEB(BASE)                                                    \
  {                                                                        \
    bf16x4 w0, w1, w2, w3;                                                 \
    w0[0] = (bf16)bv0.x; w0[1] = (bf16)bv0.y; w0[2] = (bf16)bv0.z; w0[3] = (bf16)bv0.w; \
    w1[0] = (bf16)bv1.x; w1[1] = (bf16)bv1.y; w1[2] = (bf16)bv1.z; w1[3] = (bf16)bv1.w; \
    w2[0] = (bf16)bv2.x; w2[1] = (bf16)bv2.y; w2[2] = (bf16)bv2.z; w2[3] = (bf16)bv2.w; \
    w3[0] = (bf16)bv3.x; w3[1] = (bf16)bv3.y; w3[2] = (bf16)bv3.z; w3[3] = (bf16)bv3.w; \
    *(bf16x4*)((BASE) + (h2 * 2 + 0) * BPL128 + brow * 16 + 0) = w0;       \
    *(bf16x4*)((BASE) + (h2 * 2 + 0) * BPL128 + brow * 16 + 8) = w1;       \
    *(bf16x4*)((BASE) + (h2 * 2 + 1) * BPL128 + brow * 16 + 0) = w2;       \
    *(bf16x4*)((BASE) + (h2 * 2 + 1) * BPL128 + brow * 16 + 8) = w3;       \
  }

  // prologue: stage k=0 -> buf0; prefetch regs k=32
  DN_LOADB(0);
  {
#pragma unroll
    for (int p = 0; p < 4; ++p)
      glds16(As + wv * APL + (p * 64) * 16, aG[p]);
    DN_WRITEB(Bs);
  }
  DN_LOADB(32);

  int buf = 0;
  for (int k0 = 0; k0 < Kh; k0 += 32, buf ^= 1) {
    __syncthreads();
    const int nxt = buf ^ 1;
    const int kn = k0 + 32;
    if (kn < Kh) {
#pragma unroll
      for (int p = 0; p < 4; ++p)
        glds16(As + nxt * ASZ + wv * APL + (p * 64) * 16, aG[p] + kn);
      DN_WRITEB(Bs + nxt * BSZ128);
      if (kn + 32 < Kh) DN_LOADB(kn + 32);
    }
    const char* ab = As + buf * ASZ;
    const char* bb = Bs + buf * BSZ128;
    bf16x8 aF[4];
#pragma unroll
    for (int mi = 0; mi < 4; ++mi)
      aF[mi] = *(const bf16x8*)(ab + q * APL + (wm + 16 * mi + l15) * 16);
#pragma unroll
    for (int ni = 0; ni < 8; ++ni) {
      const bf16x8 bF = *(const bf16x8*)(bb + q * BPL128 + (16 * ni + l15) * 16);
#pragma unroll
      for (int mi = 0; mi < 4; ++mi)
        acc[mi][ni] = __builtin_amdgcn_mfma_f32_16x16x32_bf16(aF[mi], bF, acc[mi][ni], 0, 0, 0);
    }
  }
#undef DN_LOADB
#undef DN_WRITEB

  float* dst = shd ? (ks ? dsS1 : dsS0) : (ks ? dsR1 : dsR0);
#pragma unroll
  for (int mi = 0; mi < 4; ++mi)
#pragma unroll
    for (int r = 0; r < 4; ++r) {
      const int rowLoc = wm + 16 * mi + q * 4 + r;
      const int row = rowStart + rowLoc;
      if (row < rowEnd) {
#pragma unroll
        for (int ni = 0; ni < 8; ++ni)
          dst[(long)row * DMODEL + (n0 + 16 * ni + l15)] = acc[mi][ni][r];
      }
    }
}

// ---------------- combine ----------------
__global__ __launch_bounds__(256)
void combine_kernel(const float* __restrict__ dsR0, const float* __restrict__ dsR1,
                    const float* __restrict__ dsS0, const float* __restrict__ dsS1,
                    const int* __restrict__ tokSlot, const float* __restrict__ tokW,
                    float* __restrict__ out) {
  const int t = blockIdx.x;
  const int j = threadIdx.x;
  const long o = (long)t * 256 + j;
  const float4 s0 = ((const float4*)dsS0)[o];
  const float4 s1 = ((const float4*)dsS1)[o];
  float4 v;
  v.x = s0.x + s1.x; v.y = s0.y + s1.y; v.z = s0.z + s1.z; v.w = s0.w + s1.w;
#pragma unroll
  for (int k = 0; k < TOPK; ++k) {
    const int s = tokSlot[t * TOPK + k];
    const float w = tokW[t * TOPK + k];
    const long so = (long)s * 256 + j;
    const float4 r0 = ((const float4*)dsR0)[so];
    const float4 r1 = ((const float4*)dsR1)[so];
    v.x += w * (r0.x + r1.x); v.y += w * (r0.y + r1.y);
    v.z += w * (r0.z + r1.z); v.w += w * (r0.w + r1.w);
  }
  ((float4*)out)[o] = v;
}

extern "C" void kernel_launch(void* const* d_in, const int* in_sizes, int n_in,
                              void* d_out, int out_size, void* d_ws, size_t ws_size,
                              hipStream_t stream) {
  const float* x  = (const float*)d_in[0];
  const float* gw = (const float*)d_in[2];
  const float* gb = (const float*)d_in[3];
  const float* gp = (const float*)d_in[4];
  const float* up = (const float*)d_in[5];
  const float* dp = (const float*)d_in[6];
  const float* sg = (const float*)d_in[7];
  const float* su = (const float*)d_in[8];
  const float* sd = (const float*)d_in[9];
  float* out = (float*)d_out;

  char* base = (char*)d_ws;
  size_t off = 0;
  auto alloc = [&](size_t bytes) -> char* {
    off = (off + 255) & ~(size_t)255;
    char* p = base + off;
    off += bytes;
    return p;
  };
  const int PADSLOTS = TTOK * TOPK + 256;
  bf16* xbf = (bf16*)alloc((size_t)TTOK * DMODEL * 2);
  bf16* interR = (bf16*)alloc((size_t)PADSLOTS * INTER * 2);
  bf16* interS = (bf16*)alloc((size_t)TTOK * NSHI * 2);
  float* dsR0 = (float*)alloc((size_t)PADSLOTS * DMODEL * 4);
  float* dsR1 = (float*)alloc((size_t)PADSLOTS * DMODEL * 4);
  float* dsS0 = (float*)alloc((size_t)TTOK * DMODEL * 4);
  float* dsS1 = (float*)alloc((size_t)TTOK * DMODEL * 4);
  float* scores = (float*)alloc((size_t)TTOK * NEXP * 4);
  int* tokIdx = (int*)alloc(TTOK * TOPK * 4);
  float* tokW = (float*)alloc(TTOK * TOPK * 4);
  int* slotTok = (int*)alloc(TTOK * TOPK * 4);
  int* tokSlot = (int*)alloc(TTOK * TOPK * 4);
  int* counts = (int*)alloc(NEXP * 4);
  int* offs = (int*)alloc((NEXP + 1) * 4);
  int* cursors = (int*)alloc(NEXP * 4);
  int* tileE = (int*)alloc(72 * 4);
  int* tileR = (int*)alloc(72 * 4);
  int* tileCnt = (int*)alloc(4);

  hipMemsetAsync(counts, 0, NEXP * 4, stream);

  scores_kernel<<<TTOK / 4, 256, 0, stream>>>(x, gw, scores, xbf);
  topk_kernel<<<TTOK / 256, 256, 0, stream>>>(scores, gb, tokIdx, tokW, counts);
  plan_kernel<<<1, 64, 0, stream>>>(counts, offs, cursors, tileE, tileR, tileCnt);
  fill_kernel<<<TTOK / 256, 256, 0, stream>>>(tokIdx, cursors, slotTok, tokSlot);

  // gateup: x = N-tiles of 32 (shared needs 32, routed exits at >=16); y = M-tiles (<=36)
  gateup_gemm<<<dim3(32, 36, 1), 256, 0, stream>>>(
      xbf, slotTok, offs, tileE, tileR, tileCnt, gp, up, sg, su, interR, interS);
  // down: x = N-tiles of 128 (8); z = split-K halves
  down_gemm<<<dim3(8, 36, 2), 256, 0, stream>>>(
      interR, interS, offs, tileE, tileR, tileCnt, dp, sd, dsR0, dsR1, dsS0, dsS1);
  combine_kernel<<<TTOK, 256, 0, stream>>>(dsR0, dsR1, dsS0, dsS1, tokSlot, tokW, out);
}